// Round 4
// baseline (776.565 us; speedup 1.0000x reference)
//
#include <hip/hip_runtime.h>

// Attention_25855703122265: B=2, S=2048, D=2048, H=16, hd=128, causal prefill.
// Round 4: I/O is FLOAT32 per the reference (previous rounds' bf16-I/O
// assumption explains the NaNs: fp32 buffers read as bf16 decode to NaN at
// ~0.4% rate). Inputs now read as float, converted to bf16 during LDS
// staging; MFMA compute unchanged; outputs written as float.
//
// Pipeline (all on `stream`):
//   1. gemm<1,A32,OBF>: q = x@Wq+bq -> q_ws (bf16, [B,H,S,hd])
//   2. gemm<1,A32,O32>: k = x@Wk+bk -> d_out present[0] (fp32, [B,H,S,hd])
//   3. gemm<1,A32,O32>: v = x@Wv+bv -> d_out present[1] (fp32, [B,H,S,hd])
//   4. attn_fwd: flash causal attention (reads fp32 k/v, bf16 q) -> attn_ws bf16
//   5. gemm<0,ABF,O32>: a = attn_ws@Wd+bd -> d_out[0:B*S*D] (fp32, [B,S,D])
//
// Workspace: q_ws 16MB @ 0, attn_ws 16MB @ +16MB. Total 32MB.

typedef unsigned short ushort_t;
typedef __attribute__((ext_vector_type(8))) short short8;   // 8 x bf16 (4 VGPR)
typedef __attribute__((ext_vector_type(4))) float f32x4;

#define MFMA16x16x32 __builtin_amdgcn_mfma_f32_16x16x32_bf16

#define S_LEN   2048
#define DMODEL  2048
#define A_ELEMS 8388608   // B*S*D
#define KV_ELEMS 8388608  // B*H*S*hd

// fast f32 -> bf16 round-to-nearest-even (finite inputs only)
__device__ __forceinline__ ushort_t f2bf(float x) {
  unsigned u = __float_as_uint(x);
  u += 0x7FFFu + ((u >> 16) & 1u);
  return (ushort_t)(u >> 16);
}
__device__ __forceinline__ unsigned pack2(float lo, float hi) {
  return (unsigned)f2bf(lo) | ((unsigned)f2bf(hi) << 16);
}
struct f8 { float v[8]; };
__device__ __forceinline__ f8 ld8f(const float* p) {
  f8 r;
  float4 a = *(const float4*)p, b = *(const float4*)(p + 4);
  r.v[0]=a.x; r.v[1]=a.y; r.v[2]=a.z; r.v[3]=a.w;
  r.v[4]=b.x; r.v[5]=b.y; r.v[6]=b.z; r.v[7]=b.w;
  return r;
}
__device__ __forceinline__ uint4 cvt8(const f8& f) {
  uint4 o;
  o.x = pack2(f.v[0], f.v[1]); o.y = pack2(f.v[2], f.v[3]);
  o.z = pack2(f.v[4], f.v[5]); o.w = pack2(f.v[6], f.v[7]);
  return o;
}

// ---------------------------------------------------------------------------
// GEMM: C[4096,2048] = A[4096,2048] @ W[2048,2048] + bias   (W fp32 [K,N])
// 128x128 block tile, BK=32, 4 waves each 64x64. bf16 MFMA core (m97-style).
// AF32: A is fp32 (converted in staging) else bf16.
// OF32: C written fp32 else bf16.
// MODE 0: C[row*2048+col] ; MODE 1: scatter to [B,H,S,hd]
// ---------------------------------------------------------------------------
template <int MODE, bool AF32, bool OF32>
__global__ void __launch_bounds__(256) gemm128(
    const void* __restrict__ Av, const float* __restrict__ W,
    const float* __restrict__ bias, void* __restrict__ Cv) {
  constexpr int K = 2048;
  __shared__ ushort_t As[128 * 32];   // [m][k] bf16
  __shared__ ushort_t Bs[128 * 32];   // [n][k] bf16 (transposed W tile)
  const int tid = threadIdx.x;
  const int w = tid >> 6, lane = tid & 63;
  const int l15 = lane & 15, quad = lane >> 4;
  const int tm = blockIdx.x & 31, tn = blockIdx.x >> 5;
  const int wr = (w >> 1) * 64, wc = (w & 1) * 64;

  // A staging: thread -> 16 contiguous elems (row ar, cols ac..ac+15)
  const int ar = tid >> 1, ac = (tid & 1) * 16;
  // W staging: thread -> k rows {bkk,bkk+1} x n cols bnn..bnn+7
  const int bkk = (tid & 15) * 2, bnn = (tid >> 4) * 8;

  f32x4 acc[4][4] = {};

  const float*    gAf = AF32 ? ((const float*)Av + (size_t)(tm * 128) * K) : nullptr;
  const ushort_t* gAb = AF32 ? nullptr : ((const ushort_t*)Av + (size_t)(tm * 128) * K);
  const float*    gW  = W + tn * 128;   // column offset

  for (int kt = 0; kt < K; kt += 32) {
    __syncthreads();
    // A tile [128][32] -> As bf16
    if (AF32) {
      f8 lo = ld8f(&gAf[(size_t)ar * K + kt + ac]);
      f8 hi = ld8f(&gAf[(size_t)ar * K + kt + ac + 8]);
      *(uint4*)&As[ar * 32 + ac]     = cvt8(lo);
      *(uint4*)&As[ar * 32 + ac + 8] = cvt8(hi);
    } else {
      *(uint4*)&As[ar * 32 + ac] =
          *(const uint4*)&gAb[(size_t)ar * K + kt + ac];
      *(uint4*)&As[ar * 32 + ac + 8] =
          *(const uint4*)&gAb[(size_t)ar * K + kt + ac + 8];
    }
    // W tile [32][128] fp32 -> Bs[n][k] bf16 transposed (pair-packed b32)
    {
      f8 r0 = ld8f(&gW[(size_t)(kt + bkk) * DMODEL + bnn]);
      f8 r1 = ld8f(&gW[(size_t)(kt + bkk + 1) * DMODEL + bnn]);
#pragma unroll
      for (int j = 0; j < 8; ++j)
        *(unsigned*)&Bs[(bnn + j) * 32 + bkk] = pack2(r0.v[j], r1.v[j]);
    }
    __syncthreads();
    short8 af[4], bf[4];
#pragma unroll
    for (int mi = 0; mi < 4; ++mi)
      af[mi] = *(const short8*)&As[(wr + mi * 16 + l15) * 32 + quad * 8];
#pragma unroll
    for (int ni = 0; ni < 4; ++ni)
      bf[ni] = *(const short8*)&Bs[(wc + ni * 16 + l15) * 32 + quad * 8];
#pragma unroll
    for (int mi = 0; mi < 4; ++mi)
#pragma unroll
      for (int ni = 0; ni < 4; ++ni)
        acc[mi][ni] = MFMA16x16x32(af[mi], bf[ni], acc[mi][ni], 0, 0, 0);
  }

  // epilogue: C/D layout col=lane&15, row=quad*4+reg  [m89/m91-verified]
  const int row0 = tm * 128 + wr;
  const int col0 = tn * 128 + wc;
  float* Cf = (float*)Cv;
  ushort_t* Cb = (ushort_t*)Cv;
#pragma unroll
  for (int ni = 0; ni < 4; ++ni) {
    const int col = col0 + ni * 16 + l15;
    const float bv = bias[col];
#pragma unroll
    for (int mi = 0; mi < 4; ++mi) {
#pragma unroll
      for (int j = 0; j < 4; ++j) {
        const int row = row0 + mi * 16 + quad * 4 + j;
        const float v = acc[mi][ni][j] + bv;
        size_t idx;
        if (MODE == 0) {
          idx = (size_t)row * DMODEL + col;
        } else {
          const int b = row >> 11, s = row & 2047, h = col >> 7, d = col & 127;
          idx = (size_t)(((b * 16 + h) * 2048 + s)) * 128 + d;
        }
        if (OF32) Cf[idx] = v; else Cb[idx] = f2bf(v);
      }
    }
  }
}

// ---------------------------------------------------------------------------
// Flash causal attention. One block = 128 q-rows of one (b,h); 4 waves x 32
// q-rows; K/V tiles of 64 rows. Q (bf16 ws) fragments in registers throughout;
// K/V read fp32 from d_out, converted to bf16 during LDS staging.
// Softmax in exp2 domain. LDS: Ks 17.4KB + Vs(T) 18.4KB + Ps 18.4KB = 54.3KB
// ---------------------------------------------------------------------------
__global__ void __launch_bounds__(256) attn_fwd(
    const ushort_t* __restrict__ Q, const float* __restrict__ Kx,
    const float* __restrict__ Vx, ushort_t* __restrict__ O) {
  __shared__ ushort_t Ks[64 * 136];   // K tile [krow][d], +8 pad
  __shared__ ushort_t Vs[128 * 72];   // V^T tile [o][krow], +8 pad
  __shared__ ushort_t Ps[128 * 72];   // P tile [qrow][krow], +8 pad
  const int tid = threadIdx.x;
  const int w = tid >> 6, lane = tid & 63;
  const int l15 = lane & 15, quad = lane >> 4;
  // qt mapping pairs heavy/light tiles 15,13,...,1,0,2,...,14 for balance
  const int p = blockIdx.x >> 5;
  const int qt = (p < 8) ? (15 - 2 * p) : (2 * (p - 8));
  const int bh = blockIdx.x & 31;
  const int q0 = qt * 128 + w * 32;           // wave's first q-row
  const size_t base = (size_t)bh * (S_LEN * 128);
  const float cs = 0.08838834764831845f * 1.4426950408889634f;  // 1/sqrt(128)*log2(e)

  // Q fragments: A-operand layout A[m=lane&15][k=quad*8+j]  [m120-verified]
  short8 qf[2][4];
#pragma unroll
  for (int mi = 0; mi < 2; ++mi)
#pragma unroll
    for (int ks = 0; ks < 4; ++ks)
      qf[mi][ks] = *(const short8*)&Q[base + (size_t)(q0 + mi * 16 + l15) * 128 +
                                      ks * 32 + quad * 8];

  f32x4 oacc[2][8] = {};
  float mrun[2][4], lrun[2][4];
#pragma unroll
  for (int mi = 0; mi < 2; ++mi)
#pragma unroll
    for (int j = 0; j < 4; ++j) { mrun[mi][j] = -1e30f; lrun[mi][j] = 0.f; }

  const int skr = tid >> 4, skc = (tid & 15) * 8;   // K staging
  const int vk = (tid & 31) * 2, vo = (tid >> 5) * 16;  // V staging (2k x 16o)

  const int nk = 2 * (qt + 1);
  for (int it = 0; it < nk; ++it) {
    const int kb = it * 64;
    __syncthreads();
    // stage K [64][128] fp32 -> Ks bf16 row-major
#pragma unroll
    for (int i = 0; i < 4; ++i) {
      const int kr = skr + i * 16;
      f8 kk = ld8f(&Kx[base + (size_t)(kb + kr) * 128 + skc]);
      *(uint4*)&Ks[kr * 136 + skc] = cvt8(kk);
    }
    // stage V transposed: Vs[o][k] = V[kb+k][o], fp32 -> bf16 pair-packed
    {
      f8 a0 = ld8f(&Vx[base + (size_t)(kb + vk) * 128 + vo]);
      f8 a1 = ld8f(&Vx[base + (size_t)(kb + vk) * 128 + vo + 8]);
      f8 b0 = ld8f(&Vx[base + (size_t)(kb + vk + 1) * 128 + vo]);
      f8 b1 = ld8f(&Vx[base + (size_t)(kb + vk + 1) * 128 + vo + 8]);
#pragma unroll
      for (int j = 0; j < 8; ++j) {
        *(unsigned*)&Vs[(vo + j) * 72 + vk]     = pack2(a0.v[j], b0.v[j]);
        *(unsigned*)&Vs[(vo + 8 + j) * 72 + vk] = pack2(a1.v[j], b1.v[j]);
      }
    }
    __syncthreads();

    // S = Q K^T  (b_frag: B[n=key][k=d] from row-major Ks)
    f32x4 sacc[2][4] = {};
#pragma unroll
    for (int ks = 0; ks < 4; ++ks) {
      short8 kf[4];
#pragma unroll
      for (int ni = 0; ni < 4; ++ni)
        kf[ni] = *(const short8*)&Ks[(ni * 16 + l15) * 136 + ks * 32 + quad * 8];
#pragma unroll
      for (int mi = 0; mi < 2; ++mi)
#pragma unroll
        for (int ni = 0; ni < 4; ++ni)
          sacc[mi][ni] = MFMA16x16x32(qf[mi][ks], kf[ni], sacc[mi][ni], 0, 0, 0);
    }

    // online softmax (rows private to the 16-lane group; shfl_xor 1/2/4/8)
#pragma unroll
    for (int mi = 0; mi < 2; ++mi) {
#pragma unroll
      for (int j = 0; j < 4; ++j) {
        const int rl = mi * 16 + quad * 4 + j;
        const int rowg = q0 + rl;
        float t0[4];
#pragma unroll
        for (int ni = 0; ni < 4; ++ni) {
          const int kg = kb + ni * 16 + l15;
          const float s = sacc[mi][ni][j] * cs;
          t0[ni] = (kg <= rowg) ? s : -1e30f;
        }
        float rm = fmaxf(fmaxf(t0[0], t0[1]), fmaxf(t0[2], t0[3]));
        rm = fmaxf(rm, __shfl_xor(rm, 1));
        rm = fmaxf(rm, __shfl_xor(rm, 2));
        rm = fmaxf(rm, __shfl_xor(rm, 4));
        rm = fmaxf(rm, __shfl_xor(rm, 8));
        const float mold = mrun[mi][j];
        const float mnew = fmaxf(mold, rm);
        const float alpha = __builtin_amdgcn_exp2f(mold - mnew);
        float rs = 0.f;
#pragma unroll
        for (int ni = 0; ni < 4; ++ni) {
          const float pe = __builtin_amdgcn_exp2f(t0[ni] - mnew);
          rs += pe;
          Ps[(w * 32 + rl) * 72 + ni * 16 + l15] = f2bf(pe);
        }
        rs += __shfl_xor(rs, 1);
        rs += __shfl_xor(rs, 2);
        rs += __shfl_xor(rs, 4);
        rs += __shfl_xor(rs, 8);
        lrun[mi][j] = lrun[mi][j] * alpha + rs;
        mrun[mi][j] = mnew;
#pragma unroll
        for (int oi = 0; oi < 8; ++oi) oacc[mi][oi][j] *= alpha;
      }
    }

    // O += P V  (P rows wave-private; Vs barrier-protected)
#pragma unroll
    for (int ks = 0; ks < 2; ++ks) {
      short8 pf[2], vf[8];
#pragma unroll
      for (int mi = 0; mi < 2; ++mi)
        pf[mi] = *(const short8*)&Ps[(w * 32 + mi * 16 + l15) * 72 +
                                     ks * 32 + quad * 8];
#pragma unroll
      for (int oi = 0; oi < 8; ++oi)
        vf[oi] = *(const short8*)&Vs[(oi * 16 + l15) * 72 + ks * 32 + quad * 8];
#pragma unroll
      for (int mi = 0; mi < 2; ++mi)
#pragma unroll
        for (int oi = 0; oi < 8; ++oi)
          oacc[mi][oi] = MFMA16x16x32(pf[mi], vf[oi], oacc[mi][oi], 0, 0, 0);
    }
  }

  // epilogue: O /= l, write merged-heads [B,S,D] (bf16 internal)
  const int b = bh >> 4, h = bh & 15;
#pragma unroll
  for (int mi = 0; mi < 2; ++mi) {
    float inv[4];
#pragma unroll
    for (int j = 0; j < 4; ++j) inv[j] = 1.f / lrun[mi][j];
#pragma unroll
    for (int oi = 0; oi < 8; ++oi) {
      const int oc = oi * 16 + l15;
#pragma unroll
      for (int j = 0; j < 4; ++j) {
        const int s = q0 + mi * 16 + quad * 4 + j;
        O[((size_t)(b * S_LEN + s)) * DMODEL + h * 128 + oc] =
            f2bf(oacc[mi][oi][j] * inv[j]);
      }
    }
  }
}

// ---------------------------------------------------------------------------
extern "C" void kernel_launch(void* const* d_in, const int* in_sizes, int n_in,
                              void* d_out, int out_size, void* d_ws,
                              size_t ws_size, hipStream_t stream) {
  const float* x  = (const float*)d_in[0];
  const float* Wq = (const float*)d_in[1];
  const float* bq = (const float*)d_in[2];
  const float* Wk = (const float*)d_in[3];
  const float* bk = (const float*)d_in[4];
  const float* Wv = (const float*)d_in[5];
  const float* bv = (const float*)d_in[6];
  const float* Wd = (const float*)d_in[7];
  const float* bd = (const float*)d_in[8];

  float* out = (float*)d_out;
  float* a_out = out;                         // [B,S,D] fp32
  float* k_out = out + A_ELEMS;               // present[0] fp32 [B,H,S,hd]
  float* v_out = out + A_ELEMS + KV_ELEMS;    // present[1] fp32 [B,H,S,hd]

  ushort_t* ws = (ushort_t*)d_ws;             // 32 MB used
  ushort_t* q_ws    = ws;                     // bf16 [B,H,S,hd]
  ushort_t* attn_ws = ws + A_ELEMS;           // bf16 [B,S,D]

  gemm128<1, true, false><<<512, 256, 0, stream>>>(x, Wq, bq, q_ws);
  gemm128<1, true, true ><<<512, 256, 0, stream>>>(x, Wk, bk, k_out);
  gemm128<1, true, true ><<<512, 256, 0, stream>>>(x, Wv, bv, v_out);
  attn_fwd<<<512, 256, 0, stream>>>(q_ws, k_out, v_out, attn_ws);
  gemm128<0, false, true><<<512, 256, 0, stream>>>(attn_ws, Wd, bd, a_out);
}

// Round 5
// 522.479 us; speedup vs baseline: 1.4863x; 1.4863x over previous
//
#include <hip/hip_runtime.h>

// Attention_25855703122265: B=2, S=2048, D=2048, H=16, hd=128, causal prefill.
// fp32 I/O (round-4 verified); bf16 MFMA compute.
//
// Round 5:
//  - prepass converts x -> bf16 (xb) and W -> bf16 transposed [N,K] once;
//    GEMM K-loops use global_load_lds(16B) m97-style, zero staging VALU.
//  - fused QKV GEMM (1536 blocks).
//  - attn v2: 128-wide K tiles, Ps aliased into Ks buffer, V staged in two
//    64-halves (52KB LDS), 256 perfectly-balanced blocks (q-tile pairs
//    (15-pr, pr) -> 17 iterations each, 1 block/CU).
//
// Memory map:
//  d_out (fp32): a [0,8.39M) | k present [8.39M,16.78M) | v [16.78M,25.17M)
//    a-region reused as scratch until proj: xb bf16 @ bytes [0,16.78M),
//    q bf16 @ bytes [16.78M,33.55M)  (dead before proj GEMM writes a).
//  d_ws: wt_q|wt_k|wt_v|wt_d (bf16 [N,K], 8.39MB each) | attn_ws bf16 16.78MB
//    = 50.3 MB total.

typedef unsigned short ushort_t;
typedef __attribute__((ext_vector_type(8))) short short8;   // 8 x bf16
typedef __attribute__((ext_vector_type(4))) float f32x4;

#define MFMA16x16x32 __builtin_amdgcn_mfma_f32_16x16x32_bf16
#define S_LEN   2048
#define DMODEL  2048
#define A_ELEMS 8388608   // B*S*D
#define W_ELEMS 4194304   // D*D

__device__ __forceinline__ ushort_t f2bf(float x) {
  unsigned u = __float_as_uint(x);
  u += 0x7FFFu + ((u >> 16) & 1u);
  return (ushort_t)(u >> 16);
}
__device__ __forceinline__ unsigned pack2(float lo, float hi) {
  return (unsigned)f2bf(lo) | ((unsigned)f2bf(hi) << 16);
}
struct f8 { float v[8]; };
__device__ __forceinline__ f8 ld8f(const float* p) {
  f8 r;
  float4 a = *(const float4*)p, b = *(const float4*)(p + 4);
  r.v[0]=a.x; r.v[1]=a.y; r.v[2]=a.z; r.v[3]=a.w;
  r.v[4]=b.x; r.v[5]=b.y; r.v[6]=b.z; r.v[7]=b.w;
  return r;
}
__device__ __forceinline__ uint4 cvt8(const f8& f) {
  uint4 o;
  o.x = pack2(f.v[0], f.v[1]); o.y = pack2(f.v[2], f.v[3]);
  o.z = pack2(f.v[4], f.v[5]); o.w = pack2(f.v[6], f.v[7]);
  return o;
}

// async global->LDS, 16B/lane; dest = wave-uniform base + lane*16
typedef const __attribute__((address_space(1))) void* gas_t;
typedef __attribute__((address_space(3))) void* las_t;
__device__ __forceinline__ void gld16(const void* g, void* l) {
  __builtin_amdgcn_global_load_lds((gas_t)(unsigned long long)g,
                                   (las_t)(unsigned)(unsigned long long)l,
                                   16, 0, 0);
}

// ---------------------------------------------------------------------------
// Prepass 1: x fp32 -> xb bf16 (straight convert, 8 elems/thread)
// ---------------------------------------------------------------------------
__global__ void __launch_bounds__(256) conv_x(const float* __restrict__ x,
                                              ushort_t* __restrict__ xb) {
  const int i = (blockIdx.x * 256 + threadIdx.x) * 8;
  f8 v = ld8f(x + i);
  *(uint4*)&xb[i] = cvt8(v);
}

// ---------------------------------------------------------------------------
// Prepass 2: W fp32 [K,N] -> wt bf16 [N,K]; 64x64 tiles; z picks weight
// ---------------------------------------------------------------------------
__global__ void __launch_bounds__(256) trans_w(
    const float* __restrict__ w0, const float* __restrict__ w1,
    const float* __restrict__ w2, const float* __restrict__ w3,
    ushort_t* __restrict__ o0, ushort_t* __restrict__ o1,
    ushort_t* __restrict__ o2, ushort_t* __restrict__ o3) {
  __shared__ float t[64][65];
  const float* src; ushort_t* dst;
  switch (blockIdx.z) {
    case 0: src = w0; dst = o0; break;
    case 1: src = w1; dst = o1; break;
    case 2: src = w2; dst = o2; break;
    default: src = w3; dst = o3; break;
  }
  const int kb = blockIdx.y * 64, nb = blockIdx.x * 64;
  const int r = threadIdx.x >> 3, c8 = (threadIdx.x & 7) * 8;
#pragma unroll
  for (int i = 0; i < 64; i += 32) {
    *(float4*)&t[r + i][c8]     = *(const float4*)&src[(size_t)(kb + r + i) * DMODEL + nb + c8];
    *(float4*)&t[r + i][c8 + 4] = *(const float4*)&src[(size_t)(kb + r + i) * DMODEL + nb + c8 + 4];
  }
  __syncthreads();
#pragma unroll
  for (int i = 0; i < 64; i += 32) {
    float tmp[8];
#pragma unroll
    for (int j = 0; j < 8; ++j) tmp[j] = t[c8 + j][r + i];
    uint4 o;
    o.x = pack2(tmp[0], tmp[1]); o.y = pack2(tmp[2], tmp[3]);
    o.z = pack2(tmp[4], tmp[5]); o.w = pack2(tmp[6], tmp[7]);
    *(uint4*)&dst[(size_t)(nb + r + i) * DMODEL + kb + c8] = o;
  }
}

// ---------------------------------------------------------------------------
// Shared GEMM core: acc[4][4] += A128x32 @ Bt128x32^T over K=2048 (m97-style)
// ---------------------------------------------------------------------------
__device__ __forceinline__ void gemm_core(
    const ushort_t* __restrict__ gA, const ushort_t* __restrict__ gB,
    ushort_t* As, ushort_t* Bs, int w, int lane, int wr, int wc,
    f32x4 acc[4][4]) {
  const int sr = lane >> 2, sc = (lane & 3) * 8;
  const int l15 = lane & 15, quad = lane >> 4;
  const ushort_t* pA = gA + sc;
  const ushort_t* pB = gB + sc;
  for (int kt = 0; kt < 2048; kt += 32) {
    __syncthreads();
#pragma unroll
    for (int i = 0; i < 4; ++i) {
      const int c = i * 4 + w;  // wave-uniform chunk (16 rows x 32 cols = 1KB)
      if (c < 8)
        gld16(pA + (size_t)(c * 16 + sr) * 2048 + kt, (void*)(As + c * 512));
      else
        gld16(pB + (size_t)((c - 8) * 16 + sr) * 2048 + kt,
              (void*)(Bs + (c - 8) * 512));
    }
    __syncthreads();
    short8 af[4], bf[4];
#pragma unroll
    for (int mi = 0; mi < 4; ++mi)
      af[mi] = *(const short8*)&As[(wr + mi * 16 + l15) * 32 + quad * 8];
#pragma unroll
    for (int ni = 0; ni < 4; ++ni)
      bf[ni] = *(const short8*)&Bs[(wc + ni * 16 + l15) * 32 + quad * 8];
#pragma unroll
    for (int mi = 0; mi < 4; ++mi)
#pragma unroll
      for (int ni = 0; ni < 4; ++ni)
        acc[mi][ni] = MFMA16x16x32(af[mi], bf[ni], acc[mi][ni], 0, 0, 0);
  }
}

// ---------------------------------------------------------------------------
// Fused QKV GEMM: wid = bx>>9 picks {q,k,v}. q -> bf16 scatter [B,H,S,hd];
// k,v -> fp32 scatter [B,H,S,hd] (present outputs).
// ---------------------------------------------------------------------------
__global__ void __launch_bounds__(256) gemm_qkv(
    const ushort_t* __restrict__ xb,
    const ushort_t* __restrict__ wtq, const ushort_t* __restrict__ wtk,
    const ushort_t* __restrict__ wtv,
    const float* __restrict__ bq, const float* __restrict__ bk,
    const float* __restrict__ bv,
    ushort_t* __restrict__ qout, float* __restrict__ kout,
    float* __restrict__ vout) {
  __shared__ ushort_t As[4096], Bs[4096];
  const int tid = threadIdx.x, w = tid >> 6, lane = tid & 63;
  const int l15 = lane & 15, quad = lane >> 4;
  const int bx = blockIdx.x, wid = bx >> 9, r = bx & 511;
  const int tm = r & 31, tn = r >> 5;
  const int wr = (w >> 1) * 64, wc = (w & 1) * 64;
  const ushort_t* Wt = wid == 0 ? wtq : (wid == 1 ? wtk : wtv);
  const float* bias = wid == 0 ? bq : (wid == 1 ? bk : bv);

  f32x4 acc[4][4] = {};
  gemm_core(xb + (size_t)(tm * 128) * 2048, Wt + (size_t)(tn * 128) * 2048,
            As, Bs, w, lane, wr, wc, acc);

  const int row0 = tm * 128 + wr, col0 = tn * 128 + wc;
#pragma unroll
  for (int ni = 0; ni < 4; ++ni) {
    const int col = col0 + ni * 16 + l15;
    const float bv_ = bias[col];
    const int h = col >> 7, d = col & 127;
#pragma unroll
    for (int mi = 0; mi < 4; ++mi) {
#pragma unroll
      for (int j = 0; j < 4; ++j) {
        const int row = row0 + mi * 16 + quad * 4 + j;
        const int b = row >> 11, s = row & 2047;
        const size_t idx = (size_t)(((b * 16 + h) * 2048 + s)) * 128 + d;
        const float v = acc[mi][ni][j] + bv_;
        if (wid == 0) qout[idx] = f2bf(v);
        else if (wid == 1) kout[idx] = v;
        else vout[idx] = v;
      }
    }
  }
}

// ---------------------------------------------------------------------------
// Proj GEMM: a[4096,2048] fp32 = attn_ws bf16 @ wt_d^T + bd
// ---------------------------------------------------------------------------
__global__ void __launch_bounds__(256) gemm_proj(
    const ushort_t* __restrict__ A, const ushort_t* __restrict__ Wt,
    const float* __restrict__ bias, float* __restrict__ C) {
  __shared__ ushort_t As[4096], Bs[4096];
  const int tid = threadIdx.x, w = tid >> 6, lane = tid & 63;
  const int l15 = lane & 15, quad = lane >> 4;
  const int tm = blockIdx.x & 31, tn = blockIdx.x >> 5;
  const int wr = (w >> 1) * 64, wc = (w & 1) * 64;

  f32x4 acc[4][4] = {};
  gemm_core(A + (size_t)(tm * 128) * 2048, Wt + (size_t)(tn * 128) * 2048,
            As, Bs, w, lane, wr, wc, acc);

  const int row0 = tm * 128 + wr, col0 = tn * 128 + wc;
#pragma unroll
  for (int ni = 0; ni < 4; ++ni) {
    const int col = col0 + ni * 16 + l15;
    const float bv_ = bias[col];
#pragma unroll
    for (int mi = 0; mi < 4; ++mi)
#pragma unroll
      for (int j = 0; j < 4; ++j) {
        const int row = row0 + mi * 16 + quad * 4 + j;
        C[(size_t)row * DMODEL + col] = acc[mi][ni][j] + bv_;
      }
  }
}

// ---------------------------------------------------------------------------
// Flash causal attention v2. 256 blocks; block bx: bh = bx&31, pr = bx>>5.
// Processes q-tiles {15-pr, pr} (128 rows each) sequentially -> exactly 17
// 128-wide K-tile iterations per block (perfect balance, 1 block/CU).
// Ks[128][136] (34816B) doubles as Ps after QK (barrier-protected);
// Vs[128][72] (18432B) staged in two 64-key halves. LDS 52KB.
// ---------------------------------------------------------------------------
__global__ void __launch_bounds__(256) attn_fwd(
    const ushort_t* __restrict__ Q, const float* __restrict__ Kx,
    const float* __restrict__ Vx, ushort_t* __restrict__ O) {
  __shared__ ushort_t Ks[128 * 136];  // K tile [key][d]; later Ps [q][key]
  __shared__ ushort_t Vs[128 * 72];   // V^T half [o][k64]
  const int tid = threadIdx.x;
  const int w = tid >> 6, lane = tid & 63;
  const int l15 = lane & 15, quad = lane >> 4;
  const int bh = blockIdx.x & 31, pr = blockIdx.x >> 5;
  const int b = bh >> 4, h = bh & 15;
  const size_t base = (size_t)bh * (S_LEN * 128);
  const float cs = 0.08838834764831845f * 1.4426950408889634f;  // 1/sqrt(128)*log2(e)

  const int kr = tid >> 1, kc0 = (tid & 1) * 64;        // K staging
  const int vk = (tid & 31) * 2, vo = (tid >> 5) * 16;  // V staging

  for (int seg = 0; seg < 2; ++seg) {
    const int qt = (seg == 0) ? (15 - pr) : pr;
    const int q0 = qt * 128 + w * 32;

    // Q fragments: A-layout A[m=lane&15][k=quad*8+j]  [m120-verified]
    short8 qf[2][4];
#pragma unroll
    for (int mi = 0; mi < 2; ++mi)
#pragma unroll
      for (int ks = 0; ks < 4; ++ks)
        qf[mi][ks] = *(const short8*)&Q[base +
            (size_t)(q0 + mi * 16 + l15) * 128 + ks * 32 + quad * 8];

    f32x4 oacc[2][8] = {};
    float mrun[2][4], lrun[2][4];
#pragma unroll
    for (int mi = 0; mi < 2; ++mi)
#pragma unroll
      for (int j = 0; j < 4; ++j) { mrun[mi][j] = -1e30f; lrun[mi][j] = 0.f; }

    for (int kt = 0; kt <= qt; ++kt) {
      const int kb = kt * 128;
      __syncthreads();  // Ks/Ps + Vs free (prev iter/seg reads done)
      // stage K [128][128] fp32 -> Ks bf16
#pragma unroll
      for (int j = 0; j < 8; ++j) {
        f8 kk = ld8f(&Kx[base + (size_t)(kb + kr) * 128 + kc0 + j * 8]);
        *(uint4*)&Ks[kr * 136 + kc0 + j * 8] = cvt8(kk);
      }
      // stage V^T half 0 (keys kb..kb+63)
      {
        f8 a0 = ld8f(&Vx[base + (size_t)(kb + vk) * 128 + vo]);
        f8 a1 = ld8f(&Vx[base + (size_t)(kb + vk) * 128 + vo + 8]);
        f8 b0 = ld8f(&Vx[base + (size_t)(kb + vk + 1) * 128 + vo]);
        f8 b1 = ld8f(&Vx[base + (size_t)(kb + vk + 1) * 128 + vo + 8]);
#pragma unroll
        for (int j = 0; j < 8; ++j) {
          *(unsigned*)&Vs[(vo + j) * 72 + vk]     = pack2(a0.v[j], b0.v[j]);
          *(unsigned*)&Vs[(vo + 8 + j) * 72 + vk] = pack2(a1.v[j], b1.v[j]);
        }
      }
      __syncthreads();

      // S = Q K^T over 128 keys
      f32x4 sacc[2][8] = {};
#pragma unroll
      for (int ks = 0; ks < 4; ++ks) {
        short8 kf[8];
#pragma unroll
        for (int ni = 0; ni < 8; ++ni)
          kf[ni] = *(const short8*)&Ks[(ni * 16 + l15) * 136 + ks * 32 + quad * 8];
#pragma unroll
        for (int mi = 0; mi < 2; ++mi)
#pragma unroll
          for (int ni = 0; ni < 8; ++ni)
            sacc[mi][ni] = MFMA16x16x32(qf[mi][ks], kf[ni], sacc[mi][ni], 0, 0, 0);
      }
      __syncthreads();  // all kf reads done; Ks buffer becomes Ps

      // online softmax (row groups private to 16-lane group)
#pragma unroll
      for (int mi = 0; mi < 2; ++mi) {
#pragma unroll
        for (int j = 0; j < 4; ++j) {
          const int rl = mi * 16 + quad * 4 + j;
          const int rowg = q0 + rl;
          float t0[8];
#pragma unroll
          for (int ni = 0; ni < 8; ++ni) {
            const int kg = kb + ni * 16 + l15;
            const float s = sacc[mi][ni][j] * cs;
            t0[ni] = (kg <= rowg) ? s : -1e30f;
          }
          float rm = t0[0];
#pragma unroll
          for (int ni = 1; ni < 8; ++ni) rm = fmaxf(rm, t0[ni]);
          rm = fmaxf(rm, __shfl_xor(rm, 1));
          rm = fmaxf(rm, __shfl_xor(rm, 2));
          rm = fmaxf(rm, __shfl_xor(rm, 4));
          rm = fmaxf(rm, __shfl_xor(rm, 8));
          const float mold = mrun[mi][j];
          const float mnew = fmaxf(mold, rm);
          const float alpha = __builtin_amdgcn_exp2f(mold - mnew);
          float rs = 0.f;
#pragma unroll
          for (int ni = 0; ni < 8; ++ni) {
            const float pe = __builtin_amdgcn_exp2f(t0[ni] - mnew);
            rs += pe;
            Ks[(w * 32 + rl) * 136 + ni * 16 + l15] = f2bf(pe);  // Ps
          }
          rs += __shfl_xor(rs, 1);
          rs += __shfl_xor(rs, 2);
          rs += __shfl_xor(rs, 4);
          rs += __shfl_xor(rs, 8);
          lrun[mi][j] = lrun[mi][j] * alpha + rs;
          mrun[mi][j] = mnew;
#pragma unroll
          for (int oi = 0; oi < 8; ++oi) oacc[mi][oi][j] *= alpha;
        }
      }

      // O += P V in two 64-key halves (pf rows are wave-private)
#pragma unroll
      for (int hh = 0; hh < 2; ++hh) {
        if (hh == 1) {
          __syncthreads();  // half-0 Vs reads done
          f8 a0 = ld8f(&Vx[base + (size_t)(kb + 64 + vk) * 128 + vo]);
          f8 a1 = ld8f(&Vx[base + (size_t)(kb + 64 + vk) * 128 + vo + 8]);
          f8 b0 = ld8f(&Vx[base + (size_t)(kb + 64 + vk + 1) * 128 + vo]);
          f8 b1 = ld8f(&Vx[base + (size_t)(kb + 64 + vk + 1) * 128 + vo + 8]);
#pragma unroll
          for (int j = 0; j < 8; ++j) {
            *(unsigned*)&Vs[(vo + j) * 72 + vk]     = pack2(a0.v[j], b0.v[j]);
            *(unsigned*)&Vs[(vo + 8 + j) * 72 + vk] = pack2(a1.v[j], b1.v[j]);
          }
          __syncthreads();
        }
#pragma unroll
        for (int ks = 0; ks < 2; ++ks) {
          short8 pf[2], vf[8];
#pragma unroll
          for (int mi = 0; mi < 2; ++mi)
            pf[mi] = *(const short8*)&Ks[(w * 32 + mi * 16 + l15) * 136 +
                                         hh * 64 + ks * 32 + quad * 8];
#pragma unroll
          for (int oi = 0; oi < 8; ++oi)
            vf[oi] = *(const short8*)&Vs[(oi * 16 + l15) * 72 + ks * 32 + quad * 8];
#pragma unroll
          for (int mi = 0; mi < 2; ++mi)
#pragma unroll
            for (int oi = 0; oi < 8; ++oi)
              oacc[mi][oi] = MFMA16x16x32(pf[mi], vf[oi], oacc[mi][oi], 0, 0, 0);
        }
      }
    }

    // epilogue: O /= l, write merged-heads bf16 [B,S,D]
#pragma unroll
    for (int mi = 0; mi < 2; ++mi) {
      float inv[4];
#pragma unroll
      for (int j = 0; j < 4; ++j) inv[j] = 1.f / lrun[mi][j];
#pragma unroll
      for (int oi = 0; oi < 8; ++oi) {
        const int oc = oi * 16 + l15;
#pragma unroll
        for (int j = 0; j < 4; ++j) {
          const int s = q0 + mi * 16 + quad * 4 + j;
          O[((size_t)(b * S_LEN + s)) * DMODEL + h * 128 + oc] =
              f2bf(oacc[mi][oi][j] * inv[j]);
        }
      }
    }
  }
}

// ---------------------------------------------------------------------------
extern "C" void kernel_launch(void* const* d_in, const int* in_sizes, int n_in,
                              void* d_out, int out_size, void* d_ws,
                              size_t ws_size, hipStream_t stream) {
  const float* x  = (const float*)d_in[0];
  const float* Wq = (const float*)d_in[1];
  const float* bq = (const float*)d_in[2];
  const float* Wk = (const float*)d_in[3];
  const float* bk = (const float*)d_in[4];
  const float* Wv = (const float*)d_in[5];
  const float* bv = (const float*)d_in[6];
  const float* Wd = (const float*)d_in[7];
  const float* bd = (const float*)d_in[8];

  float* out   = (float*)d_out;
  float* a_out = out;                     // [B,S,D] fp32 (written last)
  float* k_out = out + A_ELEMS;           // present[0] fp32 [B,H,S,hd]
  float* v_out = out + 2 * A_ELEMS;       // present[1] fp32 [B,H,S,hd]
  ushort_t* ob  = (ushort_t*)d_out;
  ushort_t* xb   = ob;                    // bf16 x, a-region bytes [0,16.78M)
  ushort_t* q_ws = ob + A_ELEMS;          // bf16 q, a-region bytes [16.78M,33.55M)

  ushort_t* ws  = (ushort_t*)d_ws;        // 50.3 MB used
  ushort_t* wtq = ws;
  ushort_t* wtk = ws + W_ELEMS;
  ushort_t* wtv = ws + 2 * (size_t)W_ELEMS;
  ushort_t* wtd = ws + 3 * (size_t)W_ELEMS;
  ushort_t* attn_ws = ws + 4 * (size_t)W_ELEMS;  // bf16 [B,S,D]

  conv_x<<<4096, 256, 0, stream>>>(x, xb);
  trans_w<<<dim3(32, 32, 4), 256, 0, stream>>>(Wq, Wk, Wv, Wd,
                                               wtq, wtk, wtv, wtd);
  gemm_qkv<<<1536, 256, 0, stream>>>(xb, wtq, wtk, wtv, bq, bk, bv,
                                     q_ws, k_out, v_out);
  attn_fwd<<<256, 256, 0, stream>>>(q_ws, k_out, v_out, attn_ws);
  gemm_proj<<<512, 256, 0, stream>>>(attn_ws, wtd, bd, a_out);
}